// Round 1
// baseline (891.556 us; speedup 1.0000x reference)
//
#include <hip/hip_runtime.h>

// FeatIterpNFMLP: trilinear grid interp (16^3 x 8ch) + MLP 8->64->64->16 (leaky 0.01)
// B=64 examples, N=8192 points each. fp32 throughout (round 1 baseline).
//
// Layout facts:
//   idx  : [64] int32
//   x    : [64, 8192, 3] f32 in [-0.5, 0.5)
//   emb  : [2048, 32768] f32 ; row -> grid [16][16][16][8] (z,y,x,c)
//   W0   : [8][64]   b0: [64]
//   W1   : [64][64]  b1: [64]
//   Wout : [64][16]  bout: [16]
//   out  : [64, 8192, 16] f32

#define NPTS_TOTAL (64 * 8192)

__global__ __launch_bounds__(256, 2) void featmlp_kernel(
    const int* __restrict__ idx,
    const float* __restrict__ x,
    const float* __restrict__ emb,
    const float* __restrict__ W0, const float* __restrict__ b0,
    const float* __restrict__ W1, const float* __restrict__ b1,
    const float* __restrict__ Wout, const float* __restrict__ bout,
    float* __restrict__ out)
{
    const int p = blockIdx.x * 256 + threadIdx.x;     // global point id
    const int b = p >> 13;                            // example id (8192 pts/example)

    // ---- locs = (x + 0.5) * 15 ----
    const float lx = (x[p * 3 + 0] + 0.5f) * 15.0f;
    const float ly = (x[p * 3 + 1] + 0.5f) * 15.0f;
    const float lz = (x[p * 3 + 2] + 0.5f) * 15.0f;

    const float fx = floorf(lx), fy = floorf(ly), fz = floorf(lz);
    const float tx = lx - fx, ty = ly - fy, tz = lz - fz;
    const int ix = (int)fx, iy = (int)fy, iz = (int)fz;

    const float* __restrict__ g = emb + ((long)idx[b] << 15);  // 32768 f32 per row

    float feat[8];
    #pragma unroll
    for (int c = 0; c < 8; ++c) feat[c] = 0.0f;

    // ---- 8-corner trilinear with reference valid-mask semantics ----
    #pragma unroll
    for (int dz = 0; dz < 2; ++dz) {
        #pragma unroll
        for (int dy = 0; dy < 2; ++dy) {
            #pragma unroll
            for (int dx = 0; dx < 2; ++dx) {
                const int jx = ix + dx, jy = iy + dy, jz = iz + dz;
                const bool valid = ((unsigned)jx < 16u) & ((unsigned)jy < 16u)
                                 & ((unsigned)jz < 16u);
                float w = (dx ? tx : 1.0f - tx)
                        * (dy ? ty : 1.0f - ty)
                        * (dz ? tz : 1.0f - tz);
                w = valid ? w : 0.0f;
                const int cx = min(max(jx, 0), 15);
                const int cy = min(max(jy, 0), 15);
                const int cz = min(max(jz, 0), 15);
                const float4* v = (const float4*)(g + ((((cz * 16) + cy) * 16 + cx) * 8));
                const float4 v0 = v[0];
                const float4 v1 = v[1];
                feat[0] += w * v0.x; feat[1] += w * v0.y;
                feat[2] += w * v0.z; feat[3] += w * v0.w;
                feat[4] += w * v1.x; feat[5] += w * v1.y;
                feat[6] += w * v1.z; feat[7] += w * v1.w;
            }
        }
    }

    // ---- layer 0: 8 -> 64, leaky relu ----
    float h[64];
    #pragma unroll
    for (int j = 0; j < 64; ++j) {
        float a = b0[j];
        #pragma unroll
        for (int k = 0; k < 8; ++k) a += feat[k] * W0[k * 64 + j];
        h[j] = fmaxf(a, 0.01f * a);   // leaky relu, branchless
    }

    // ---- layer 1: 64 -> 64, leaky relu ----
    float h2[64];
    #pragma unroll
    for (int j = 0; j < 64; ++j) {
        float a = b1[j];
        #pragma unroll
        for (int k = 0; k < 64; ++k) a += h[k] * W1[k * 64 + j];
        h2[j] = fmaxf(a, 0.01f * a);
    }

    // ---- layer 2: 64 -> 16 ----
    float* __restrict__ o = out + (long)p * 16;
    #pragma unroll
    for (int j = 0; j < 16; ++j) {
        float a = bout[j];
        #pragma unroll
        for (int k = 0; k < 64; ++k) a += h2[k] * Wout[k * 16 + j];
        o[j] = a;
    }
}

extern "C" void kernel_launch(void* const* d_in, const int* in_sizes, int n_in,
                              void* d_out, int out_size, void* d_ws, size_t ws_size,
                              hipStream_t stream) {
    const int*   idx  = (const int*)  d_in[0];
    const float* x    = (const float*)d_in[1];
    const float* emb  = (const float*)d_in[2];
    const float* W0   = (const float*)d_in[3];
    const float* b0   = (const float*)d_in[4];
    const float* W1   = (const float*)d_in[5];
    const float* b1   = (const float*)d_in[6];
    const float* Wout = (const float*)d_in[7];
    const float* bout = (const float*)d_in[8];
    float* out = (float*)d_out;

    const int nblocks = NPTS_TOTAL / 256;   // 2048
    featmlp_kernel<<<nblocks, 256, 0, stream>>>(idx, x, emb, W0, b0, W1, b1,
                                                Wout, bout, out);
}

// Round 2
// 46.590 us; speedup vs baseline: 19.1362x; 19.1362x over previous
//
#include <hip/hip_runtime.h>

// FeatIterpNFMLP: trilinear grid interp (16^3 x 8ch) + MLP 8->64->64->16 (leaky 0.01)
// Round 2: MFMA (32x32x16 bf16), transposed formulation D[j][p] = sum_k W[k][j]*act[p][k].
// One wave = 64 points. Weights live in registers as A-fragments (bf16, packed once).
// Layer handoff fully in-register: leaky-relu -> v_cvt_pk_bf16_f32 -> v_permlane32_swap_b32.
// No LDS, no barriers.

typedef __attribute__((ext_vector_type(8)))  short short8;
typedef __attribute__((ext_vector_type(16))) float f32x16;
typedef __attribute__((ext_vector_type(4)))  int   int4v;

static __device__ __forceinline__ unsigned cvt_pk_bf16(float lo, float hi) {
    unsigned r;
    asm("v_cvt_pk_bf16_f32 %0, %1, %2" : "=v"(r) : "v"(lo), "v"(hi));
    return r;
}
// v_permlane32_swap_b32 vdst, vsrc:
//   vdst'[l<32]=vdst[l<32]; vdst'[l>=32]=vsrc[l-32]; vsrc'[l<32]=vdst[l+32]; vsrc'[l>=32]=vsrc[l>=32]
static __device__ __forceinline__ void permswap(unsigned &a, unsigned &b) {
    asm("v_permlane32_swap_b32 %0, %1" : "+v"(a), "+v"(b));
}
static __device__ __forceinline__ short8 as_s8(int4v v) {
    return __builtin_bit_cast(short8, v);
}

// leaky-relu the 2x2 accum tiles in place, then repack as B-fragments for the next
// layer: b[ct][kt] where k (=prev hidden j) = kt*16 + 8*(lane>>5) + {0..7}.
// acc layout per tile: col(point)=lane&31, row(j)=(r&3)+8*(r>>2)+4*(lane>>5).
static __device__ __forceinline__ void relu_pack(f32x16 acc[2][2], int4v bfr[2][4]) {
    #pragma unroll
    for (int rt = 0; rt < 2; ++rt)
        #pragma unroll
        for (int ct = 0; ct < 2; ++ct)
            #pragma unroll
            for (int r = 0; r < 16; ++r) {
                float a = acc[rt][ct][r];
                acc[rt][ct][r] = fmaxf(a, 0.01f * a);
            }
    #pragma unroll
    for (int ct = 0; ct < 2; ++ct)
        #pragma unroll
        for (int kt = 0; kt < 4; ++kt) {
            const int rs = kt >> 1;          // source row-tile (j block of 32)
            const int base = (kt & 1) * 8;   // quad pair within tile: j-offsets {0-7} or {16-23}+...
            unsigned pa0 = cvt_pk_bf16(acc[rs][ct][base + 0], acc[rs][ct][base + 1]);
            unsigned pa1 = cvt_pk_bf16(acc[rs][ct][base + 2], acc[rs][ct][base + 3]);
            unsigned pb0 = cvt_pk_bf16(acc[rs][ct][base + 4], acc[rs][ct][base + 5]);
            unsigned pb1 = cvt_pk_bf16(acc[rs][ct][base + 6], acc[rs][ct][base + 7]);
            permswap(pa0, pb0);   // -> m0 (k+{0,1}), m2 (k+{4,5})
            permswap(pa1, pb1);   // -> m1 (k+{2,3}), m3 (k+{6,7})
            bfr[ct][kt][0] = (int)pa0;
            bfr[ct][kt][1] = (int)pa1;
            bfr[ct][kt][2] = (int)pb0;
            bfr[ct][kt][3] = (int)pb1;
        }
}

__global__ __launch_bounds__(256, 2) void featmlp_mfma(
    const int* __restrict__ idx,
    const float* __restrict__ x,
    const float* __restrict__ emb,
    const float* __restrict__ W0, const float* __restrict__ b0,
    const float* __restrict__ W1, const float* __restrict__ b1,
    const float* __restrict__ Wout, const float* __restrict__ bout,
    float* __restrict__ out)
{
    const int lane = threadIdx.x & 63;
    const int half = lane >> 5;     // 0: k 0-7, 1: k 8-15 within a K=16 tile
    const int l31  = lane & 31;

    // ---------------- weight A-fragments (bf16, registers, loaded once) -------------
    // A[row=j][k] = W[k][j]; lane holds row j = rt*32 + l31, k = kt*16 + half*8 + 2m+{0,1}
    int4v w0f[2];          // layer0: K=8 padded to 16 (k>=8 multiplied by zero B)
    int4v w1f[2][4];
    int4v wof[4];          // layer2: rows j>=16 are garbage (clamped), never stored
    #pragma unroll
    for (int rt = 0; rt < 2; ++rt) {
        const int j = rt * 32 + l31;
        #pragma unroll
        for (int m = 0; m < 4; ++m) {
            const int k0 = (half * 8 + 2 * m) & 7;       // clamp: k>=8 lanes read junk (x0)
            const int k1 = (half * 8 + 2 * m + 1) & 7;
            w0f[rt][m] = (int)cvt_pk_bf16(W0[k0 * 64 + j], W0[k1 * 64 + j]);
        }
        #pragma unroll
        for (int kt = 0; kt < 4; ++kt)
            #pragma unroll
            for (int m = 0; m < 4; ++m) {
                const int k = kt * 16 + half * 8 + 2 * m;
                w1f[rt][kt][m] = (int)cvt_pk_bf16(W1[k * 64 + j], W1[(k + 1) * 64 + j]);
            }
    }
    {
        const int jo = l31 < 15 ? l31 : 15;              // clamp: j>=16 rows unused
        #pragma unroll
        for (int kt = 0; kt < 4; ++kt)
            #pragma unroll
            for (int m = 0; m < 4; ++m) {
                const int k = kt * 16 + half * 8 + 2 * m;
                wof[kt][m] = (int)cvt_pk_bf16(Wout[k * 16 + jo], Wout[(k + 1) * 16 + jo]);
            }
    }

    // ---------------- per-wave point group ------------------------------------------
    const int group = blockIdx.x * 4 + (threadIdx.x >> 6);   // 8192 groups total
    const long p0 = (long)group * 64;
    const int  b  = group >> 7;                              // 128 groups / example
    const float* __restrict__ g = emb + ((long)idx[b] << 15);

    // ---- trilinear interp for this lane's point ----
    const long p = p0 + lane;
    const float lx = (x[p * 3 + 0] + 0.5f) * 15.0f;
    const float ly = (x[p * 3 + 1] + 0.5f) * 15.0f;
    const float lz = (x[p * 3 + 2] + 0.5f) * 15.0f;
    const float fx = floorf(lx), fy = floorf(ly), fz = floorf(lz);
    const float tx = lx - fx, ty = ly - fy, tz = lz - fz;
    const int ix = (int)fx, iy = (int)fy, iz = (int)fz;

    float feat[8];
    #pragma unroll
    for (int c = 0; c < 8; ++c) feat[c] = 0.0f;
    #pragma unroll
    for (int dz = 0; dz < 2; ++dz)
        #pragma unroll
        for (int dy = 0; dy < 2; ++dy)
            #pragma unroll
            for (int dx = 0; dx < 2; ++dx) {
                const int jx = ix + dx, jy = iy + dy, jz = iz + dz;
                const bool valid = ((unsigned)jx < 16u) & ((unsigned)jy < 16u)
                                 & ((unsigned)jz < 16u);
                float w = (dx ? tx : 1.0f - tx)
                        * (dy ? ty : 1.0f - ty)
                        * (dz ? tz : 1.0f - tz);
                w = valid ? w : 0.0f;
                const int cx = min(max(jx, 0), 15);
                const int cy = min(max(jy, 0), 15);
                const int cz = min(max(jz, 0), 15);
                const float4* v = (const float4*)(g + ((((cz * 16) + cy) * 16 + cx) * 8));
                const float4 v0 = v[0];
                const float4 v1 = v[1];
                feat[0] += w * v0.x; feat[1] += w * v0.y;
                feat[2] += w * v0.z; feat[3] += w * v0.w;
                feat[4] += w * v1.x; feat[5] += w * v1.y;
                feat[6] += w * v1.z; feat[7] += w * v1.w;
            }

    // ---- feat -> B-fragments for layer 0 (K=16, ch 8-15 zero) ----
    // B[k=ch][p]: ct0 lanes<32 = own feat, ct1 lanes<32 = partner feat; lanes>=32 = 0.
    int4v bf0[2];
    #pragma unroll
    for (int m = 0; m < 4; ++m) {
        unsigned a = cvt_pk_bf16(feat[2 * m], feat[2 * m + 1]);
        unsigned z = 0u;
        permswap(a, z);
        bf0[0][m] = (int)a;
        bf0[1][m] = (int)z;
    }

    // ---- layer 0: h[64][64pts] = leaky(W0^T @ feat^T + b0) ----
    f32x16 acc0[2][2];
    #pragma unroll
    for (int rt = 0; rt < 2; ++rt) {
        f32x16 bias;
        #pragma unroll
        for (int q = 0; q < 4; ++q) {
            const float4 v = *(const float4*)(b0 + rt * 32 + q * 8 + half * 4);
            bias[4 * q + 0] = v.x; bias[4 * q + 1] = v.y;
            bias[4 * q + 2] = v.z; bias[4 * q + 3] = v.w;
        }
        #pragma unroll
        for (int ct = 0; ct < 2; ++ct)
            acc0[rt][ct] = __builtin_amdgcn_mfma_f32_32x32x16_bf16(
                as_s8(w0f[rt]), as_s8(bf0[ct]), bias, 0, 0, 0);
    }

    int4v b1f[2][4];
    relu_pack(acc0, b1f);

    // ---- layer 1: h2 = leaky(W1^T @ h + b1) ----
    f32x16 acc1[2][2];
    #pragma unroll
    for (int rt = 0; rt < 2; ++rt) {
        f32x16 bias;
        #pragma unroll
        for (int q = 0; q < 4; ++q) {
            const float4 v = *(const float4*)(b1 + rt * 32 + q * 8 + half * 4);
            bias[4 * q + 0] = v.x; bias[4 * q + 1] = v.y;
            bias[4 * q + 2] = v.z; bias[4 * q + 3] = v.w;
        }
        #pragma unroll
        for (int ct = 0; ct < 2; ++ct) {
            f32x16 a = bias;
            #pragma unroll
            for (int kt = 0; kt < 4; ++kt)
                a = __builtin_amdgcn_mfma_f32_32x32x16_bf16(
                    as_s8(w1f[rt][kt]), as_s8(b1f[ct][kt]), a, 0, 0, 0);
            acc1[rt][ct] = a;
        }
    }

    int4v b2f[2][4];
    relu_pack(acc1, b2f);

    // ---- layer 2: out = Wout^T @ h2 + bout (rows j<16 valid) ----
    f32x16 bb;
    #pragma unroll
    for (int i = 0; i < 4; ++i) {
        bb[i]      = bout[half * 4 + i];
        bb[4 + i]  = bout[8 + half * 4 + i];
        bb[8 + i]  = 0.0f;
        bb[12 + i] = 0.0f;
    }
    #pragma unroll
    for (int ct = 0; ct < 2; ++ct) {
        f32x16 a = bb;
        #pragma unroll
        for (int kt = 0; kt < 4; ++kt)
            a = __builtin_amdgcn_mfma_f32_32x32x16_bf16(
                as_s8(wof[kt]), as_s8(b2f[ct][kt]), a, 0, 0, 0);
        // store: j = (r&3) + 8*(r>>2) + 4*half, p = p0 + ct*32 + l31; j<16 => regs 0-7
        float* o = out + (p0 + ct * 32 + l31) * 16;
        *(float4*)(o + half * 4)     = make_float4(a[0], a[1], a[2], a[3]);
        *(float4*)(o + 8 + half * 4) = make_float4(a[4], a[5], a[6], a[7]);
    }
}

extern "C" void kernel_launch(void* const* d_in, const int* in_sizes, int n_in,
                              void* d_out, int out_size, void* d_ws, size_t ws_size,
                              hipStream_t stream) {
    const int*   idx  = (const int*)  d_in[0];
    const float* x    = (const float*)d_in[1];
    const float* emb  = (const float*)d_in[2];
    const float* W0   = (const float*)d_in[3];
    const float* b0   = (const float*)d_in[4];
    const float* W1   = (const float*)d_in[5];
    const float* b1   = (const float*)d_in[6];
    const float* Wout = (const float*)d_in[7];
    const float* bout = (const float*)d_in[8];
    float* out = (float*)d_out;

    // 64*8192 points / 64 per wave = 8192 waves; 4 waves per block -> 2048 blocks
    featmlp_mfma<<<2048, 256, 0, stream>>>(idx, x, emb, W0, b0, W1, b1,
                                           Wout, bout, out);
}